// Round 9
// baseline (273.292 us; speedup 1.0000x reference)
//
#include <hip/hip_runtime.h>

typedef unsigned short u16;
typedef unsigned int   u32;
typedef short  short8   __attribute__((ext_vector_type(8)));
typedef float  floatx4  __attribute__((ext_vector_type(4)));
typedef u16    ushortx2 __attribute__((ext_vector_type(2)));
typedef u16    ushortx4 __attribute__((ext_vector_type(4)));

__device__ __forceinline__ float bf2f(u16 u) {
  union { u32 i; float f; } v; v.i = ((u32)u) << 16; return v.f;
}
__device__ __forceinline__ u16 f2bf(float x) {
  union { float f; u32 i; } v; v.f = x;
  u32 r = v.i + 0x7FFFu + ((v.i >> 16) & 1u);   // round-to-nearest-even
  return (u16)(r >> 16);
}

#if __has_builtin(__builtin_amdgcn_exp2f)
#define EXP2F(x) __builtin_amdgcn_exp2f(x)
#else
#define EXP2F(x) __exp2f(x)
#endif

// async global->LDS, 16B per lane; LDS dest = wave-uniform base + lane*16
#define GLOAD_LDS16(gptr, lptr)                                                   \
  __builtin_amdgcn_global_load_lds(                                               \
      (const __attribute__((address_space(1))) void*)(gptr),                      \
      (__attribute__((address_space(3))) void*)(lptr), 16, 0, 0)

#define WAITV(n) asm volatile("s_waitcnt vmcnt(" #n ")" ::: "memory")
#define WAITL    asm volatile("s_waitcnt lgkmcnt(0)" ::: "memory")
#define BAR      __builtin_amdgcn_s_barrier()

// ---------------------------------------------------------------------------
// fp32 -> bf16 bulk convert, all 5 tensors in one launch (blockIdx.y selects).
// ---------------------------------------------------------------------------
__global__ __launch_bounds__(256) void cvt_all(
    const floatx4* __restrict__ x,  const floatx4* __restrict__ wq,
    const floatx4* __restrict__ wk, const floatx4* __restrict__ wv,
    const floatx4* __restrict__ wo,
    ushortx4* __restrict__ xb, ushortx4* __restrict__ wqkv,
    ushortx4* __restrict__ wob) {
  int i = blockIdx.x * 256 + threadIdx.x;
  const floatx4* in; ushortx4* out;
  switch (blockIdx.y) {
    case 0:  in = x;  out = xb; break;
    case 1:  in = wq; out = wqkv; break;
    case 2:  in = wk; out = wqkv + (size_t)1048576; break;   // 2048*2048/4
    case 3:  in = wv; out = wqkv + (size_t)2097152; break;
    default: in = wo; out = wob; break;
  }
  floatx4 v = in[i];
  ushortx4 o;
  o.x = f2bf(v.x); o.y = f2bf(v.y); o.z = f2bf(v.z); o.w = f2bf(v.w);
  out[i] = o;
}

// ---------------------------------------------------------------------------
// 256x192 8-wave BT-GEMM, BK=64, 3-phase K-loop (16 MFMA/phase), counted
// vmcnt.  R9 = R3 fragment handling (R8's cross-phase reg pipelining
// REVERTED: +32 VGPR, scratch spill, -4%) + DEEPENED PREFETCH: all 7 of
// tile t+1's gloads issue at P1(t) (R3 spread them P1/P2/P3, so each chunk
// was waited 1-2 phases (~300-500cy) after issue — under HBM latency).
//
// Per-tile gload FIFO (7, issue order): g1,g2=A-h0 | g3=B0 | g4=B1 | g5=B2
// | g6,g7=A-h1.  Reads: P1 consumes g1..g4, P2 consumes g5..g7, P3 none.
// Waits (each one phase before the consuming reads; never vmcnt(0) in loop):
//   P1: ds A-h0,B0,B1 | st g1'..g7' | vmcnt(7) -> g5-g7(t) in  | bar | 16 MFMA
//   P2: ds B2,A-h1    |             |                          | bar | 16 MFMA
//   P3:               | vmcnt(3) -> g1'-g4'(t+1) in            | bar | 16 MFMA
// Latency cover: g5-g7(t) issued P1(t-1), waited P1(t) = 3 phases (~770cy);
// g1-g4(t+1) issued P1(t), waited P3(t) = 2 phases (~510cy).
// WAR: staging at P1(t) writes buffer(t-1); every wave's reads of that
// buffer are consumed by MFMAs issued BEFORE P3(t-1)'s barrier (MFMA issue
// forces lgkm retire), and staging follows that barrier.  Trailing P3 MFMAs
// are register-only.
// ---------------------------------------------------------------------------
__global__ __launch_bounds__(512, 2) void gemm256_bt(
    const u16* __restrict__ A, const u16* __restrict__ B, u16* __restrict__ C,
    int N, int K, int lda, int ldb, int ldc) {
  // bijective XCD swizzle (gridDim.x % 8 == 0)
  const int cpx = gridDim.x >> 3;
  const int wg = ((int)blockIdx.x & 7) * cpx + ((int)blockIdx.x >> 3);
  const int ntn = N / 192;
  const int m0 = (wg / ntn) << 8;
  const int n0 = (wg % ntn) * 192;

  __shared__ __align__(16) u16 As[2][256][64];
  __shared__ __align__(16) u16 Bs[2][192][64];

  const int t = threadIdx.x;
  const int lane = t & 63;
  const int wave = t >> 6;
  const int wr = wave >> 2;          // 0..1
  const int wc = wave & 3;           // 0..3
  const int quad = lane >> 4;
  const int mrow = lane & 15;
  const int sw = mrow & 7;

  // staging: per gload, wave writes 1 KiB = 8 rows x 8 segs; global col-seg
  // pre-swizzled so a linear LDS write realizes the seg-XOR layout.
  const int srow = lane >> 3;                    // 0..7
  const int gso  = ((lane & 7) ^ srow) << 3;     // u16 col offset

  const u16* gA = A + (size_t)(m0 + (wave << 3) + srow) * lda + gso;
  const u16* gB = B + (size_t)(n0 + (wave << 3) + srow) * ldb + gso;

  floatx4 acc[8][3] = {};
  short8 afr[4][2], bfr[3][2];

  const int NT = K >> 6;                         // K-tiles (NT >= 2)

#define ST_A(nb, h, kt)                                                        \
  do {                                                                         \
    GLOAD_LDS16(gA + (size_t)((h) * 128) * lda + ((kt) << 6),                  \
                &As[nb][(h) * 128 + (wave << 3)][0]);                          \
    GLOAD_LDS16(gA + (size_t)((h) * 128 + 64) * lda + ((kt) << 6),             \
                &As[nb][(h) * 128 + 64 + (wave << 3)][0]);                     \
  } while (0)
#define ST_B1(nb, c, kt)                                                       \
  do {                                                                         \
    GLOAD_LDS16(gB + (size_t)((c) * 64) * ldb + ((kt) << 6),                   \
                &Bs[nb][(c) * 64 + (wave << 3)][0]);                           \
  } while (0)

  // A frags i0..3 from rows base_row + i*16 + mrow of As[bf]
#define LDA4(bf, base_row)                                                     \
  do {                                                                         \
    _Pragma("unroll") for (int i_ = 0; i_ < 4; i_++)                           \
      _Pragma("unroll") for (int kk_ = 0; kk_ < 2; kk_++)                      \
        afr[i_][kk_] = *(const short8*)&As[bf][(base_row) + (i_ << 4) + mrow]  \
                            [(((kk_ << 2) | quad) ^ sw) << 3];                 \
  } while (0)
  // B frag j from rows j*64 + wc*16 + mrow of Bs[bf]
#define LDB1(bf, j)                                                            \
  do {                                                                         \
    _Pragma("unroll") for (int kk_ = 0; kk_ < 2; kk_++)                        \
      bfr[j][kk_] = *(const short8*)&Bs[bf][(j) * 64 + (wc << 4) + mrow]       \
          [(((kk_ << 2) | quad) ^ sw) << 3];                                   \
  } while (0)
  // one sub-block: 4 i x 1 j x 2 kk = 8 MFMA (afr holds the i-set for ilo)
#define MMQ8(ilo, j)                                                           \
  do {                                                                         \
    __builtin_amdgcn_s_setprio(1);                                             \
    _Pragma("unroll") for (int kk_ = 0; kk_ < 2; kk_++)                        \
      _Pragma("unroll") for (int i_ = 0; i_ < 4; i_++)                         \
        acc[(ilo) + i_][j] = __builtin_amdgcn_mfma_f32_16x16x32_bf16(          \
            afr[i_][kk_], bfr[j][kk_], acc[(ilo) + i_][j], 0, 0, 0);           \
    __builtin_amdgcn_s_setprio(0);                                             \
  } while (0)

  // prologue: stage tile 0 in FIFO order g1..g7
  ST_A(0, 0, 0); ST_B1(0, 0, 0); ST_B1(0, 1, 0); ST_B1(0, 2, 0); ST_A(0, 1, 0);
  WAITV(3);                                    // g1..g4(t0) resident for P1
  BAR;

  for (int kt = 0; kt < NT - 1; kt++) {
    const int bf = kt & 1, nb = bf ^ 1;
    // ---- P1: reads g1..g4(kt); issues ALL of tile kt+1 ----
    LDA4(bf, (wr << 6));                       // A-h0 rows
    LDB1(bf, 0);                               // B-c0
    LDB1(bf, 1);                               // B-c1
    ST_A(nb, 0, kt + 1);                       // g1',g2'
    ST_B1(nb, 0, kt + 1);                      // g3'
    ST_B1(nb, 1, kt + 1);                      // g4'
    ST_B1(nb, 2, kt + 1);                      // g5'
    ST_A(nb, 1, kt + 1);                       // g6',g7'
    WAITV(7);                                  // retire g5-g7(kt) (P2 reads)
    BAR;
    MMQ8(0, 0);
    MMQ8(0, 1);
    // ---- P2: reads g5..g7(kt) ----
    LDB1(bf, 2);                               // B-c2
    BAR;
    MMQ8(0, 2);
    LDA4(bf, 128 + (wr << 6));                 // A-h1
    MMQ8(4, 0);
    // ---- P3: register-only MFMAs ----
    WAITV(3);                                  // retire g1'-g4' (next P1 reads)
    BAR;
    MMQ8(4, 1);
    MMQ8(4, 2);
  }
  {                                            // last tile, no staging
    const int bf = (NT - 1) & 1;
    LDA4(bf, (wr << 6));
    LDB1(bf, 0);
    LDB1(bf, 1);
    WAITV(0);                                  // g5..g7 resident
    BAR;
    MMQ8(0, 0);
    MMQ8(0, 1);
    LDB1(bf, 2);
    BAR;
    MMQ8(0, 2);
    LDA4(bf, 128 + (wr << 6));
    MMQ8(4, 0);
    BAR;
    MMQ8(4, 1);
    MMQ8(4, 2);
  }

  // epilogue. C/D layout: col = lane&15, row = quad*4 + reg
#pragma unroll
  for (int i = 0; i < 8; i++) {
    int row0 = m0 + ((i >= 4) ? 128 : 0) + (wr << 6) + ((i & 3) << 4) + (quad << 2);
#pragma unroll
    for (int j = 0; j < 3; j++) {
      int col = n0 + j * 64 + (wc << 4) + mrow;
#pragma unroll
      for (int r = 0; r < 4; r++)
        C[(size_t)(row0 + r) * ldc + col] = f2bf(acc[i][j][r]);
    }
  }
#undef ST_A
#undef ST_B1
#undef LDA4
#undef LDB1
#undef MMQ8
}

// ---------------------------------------------------------------------------
// Output projection: out[m][n] = sum_k AT[m][k]*WOb[n][k], fp32 out direct.
// 128x128 tile, 256 blocks (full fill), 2 blocks/CU, 2-phase counted vmcnt.
// R9: all 8 stages issued at P1 (deeper prefetch, same pattern as the QKV
// kernel); explicit lgkmcnt(0) before P2's barrier closes the tail-read WAR
// window that earlier staging placement left implicit.
// FIFO: g1..g4=A0..3, g5,g6=B0,B2, g7,g8=B1,B3.  P1 reads g1-g6, P2 reads
// g7,g8.  P1: issue 8, vmcnt(8) (retire g7,g8(t)); P2: vmcnt(2) (retire
// g1-g6(t+1)).  Prologue vmcnt(2); last tile vmcnt(0) at P1.
// ---------------------------------------------------------------------------
__global__ __launch_bounds__(256, 2) void gemm_out(
    const u16* __restrict__ A, const u16* __restrict__ B,
    float* __restrict__ C) {
  // bijective XCD swizzle over 256 blocks
  const int wg = ((int)blockIdx.x & 7) * 32 + ((int)blockIdx.x >> 3);
  const int m0 = (wg >> 4) << 7;
  const int n0 = (wg & 15) << 7;

  __shared__ __align__(16) u16 As[2][128][64];
  __shared__ __align__(16) u16 Bs[2][128][64];

  const int t = threadIdx.x;
  const int lane = t & 63;
  const int wave = t >> 6;           // 0..3
  const int wr = wave >> 1;          // 0..1
  const int wc = wave & 1;           // 0..1
  const int quad = lane >> 4;
  const int mrow = lane & 15;
  const int sw = mrow & 7;

  const int srow = lane >> 3;                    // 0..7
  const int gso  = ((lane & 7) ^ srow) << 3;     // pre-swizzled col seg

  const u16* gA = A + (size_t)(m0 + (wave << 3) + srow) * 2048 + gso;
  const u16* gB = B + (size_t)(n0 + (wave << 3) + srow) * 2048 + gso;

  floatx4 acc[4][4] = {};
  short8 afr[4][2], bfr[4][2];

  const int NT = 32;                             // 2048/64

#define OST_A(nb, p, kt)                                                       \
  GLOAD_LDS16(gA + (size_t)((p) * 32) * 2048 + ((kt) << 6),                    \
              &As[nb][(p) * 32 + (wave << 3)][0])
#define OST_B(nb, p, kt)                                                       \
  GLOAD_LDS16(gB + (size_t)((p) * 32) * 2048 + ((kt) << 6),                    \
              &Bs[nb][(p) * 32 + (wave << 3)][0])

#define OLDA(bf)                                                               \
  do {                                                                         \
    _Pragma("unroll") for (int i_ = 0; i_ < 4; i_++)                           \
      _Pragma("unroll") for (int kk_ = 0; kk_ < 2; kk_++)                      \
        afr[i_][kk_] = *(const short8*)&As[bf][(wr << 6) + (i_ << 4) + mrow]   \
                            [(((kk_ << 2) | quad) ^ sw) << 3];                 \
  } while (0)
#define OLDB2(bf, jlo)                                                         \
  do {                                                                         \
    _Pragma("unroll") for (int j_ = 0; j_ < 2; j_++)                           \
      _Pragma("unroll") for (int kk_ = 0; kk_ < 2; kk_++)                      \
        bfr[(jlo) + j_][kk_] =                                                 \
            *(const short8*)&Bs[bf][(wc << 6) + (((jlo) + j_) << 4) + mrow]    \
                [(((kk_ << 2) | quad) ^ sw) << 3];                             \
  } while (0)
#define OMM16(jlo)                                                             \
  do {                                                                         \
    __builtin_amdgcn_s_setprio(1);                                             \
    _Pragma("unroll") for (int kk_ = 0; kk_ < 2; kk_++)                        \
      _Pragma("unroll") for (int i_ = 0; i_ < 4; i_++)                         \
        _Pragma("unroll") for (int j_ = 0; j_ < 2; j_++)                       \
          acc[i_][(jlo) + j_] = __builtin_amdgcn_mfma_f32_16x16x32_bf16(       \
              afr[i_][kk_], bfr[(jlo) + j_][kk_], acc[i_][(jlo) + j_], 0, 0, 0);\
    __builtin_amdgcn_s_setprio(0);                                             \
  } while (0)

  // prologue: FIFO g1..g8 = A0,A1,A2,A3,B0,B2,B1,B3
  OST_A(0, 0, 0); OST_A(0, 1, 0); OST_A(0, 2, 0); OST_A(0, 3, 0);
  OST_B(0, 0, 0); OST_B(0, 2, 0); OST_B(0, 1, 0); OST_B(0, 3, 0);
  WAITV(2);                                    // g1..g6 resident for P1
  BAR;

  for (int kt = 0; kt < NT - 1; kt++) {
    const int bf = kt & 1, nb = bf ^ 1;
    // ---- P1: reads g1-g6(kt); issues ALL of tile kt+1 ----
    OLDA(bf);
    OLDB2(bf, 0);
    OST_A(nb, 0, kt + 1); OST_A(nb, 1, kt + 1);
    OST_A(nb, 2, kt + 1); OST_A(nb, 3, kt + 1);
    OST_B(nb, 0, kt + 1); OST_B(nb, 2, kt + 1);
    OST_B(nb, 1, kt + 1); OST_B(nb, 3, kt + 1);
    WAITV(8);                                  // retire g7,g8(kt)
    BAR;
    OMM16(0);
    // ---- P2: reads g7,g8(kt) ----
    OLDB2(bf, 2);
    WAITV(2);                                  // retire g1-g6(kt+1)
    WAITL;                                     // bfr reads in regs pre-barrier
    BAR;
    OMM16(2);
  }
  {                                            // last tile, no staging
    const int bf = (NT - 1) & 1;
    OLDA(bf);
    OLDB2(bf, 0);
    WAITV(0);                                  // g7,g8 resident
    BAR;
    OMM16(0);
    OLDB2(bf, 2);
    OMM16(2);
  }

  // epilogue: fp32 direct. C/D layout: col = lane&15, row = quad*4 + reg
#pragma unroll
  for (int i = 0; i < 4; i++) {
    int row0 = m0 + (wr << 6) + (i << 4) + (quad << 2);
#pragma unroll
    for (int j = 0; j < 4; j++) {
      int col = n0 + (wc << 6) + (j << 4) + mrow;
#pragma unroll
      for (int r = 0; r < 4; r++)
        C[(size_t)(row0 + r) * 2048 + col] = acc[i][j][r];
    }
  }
#undef OST_A
#undef OST_B
#undef OLDA
#undef OLDB2
#undef OMM16
}

// ---------------------------------------------------------------------------
// Merged aux kernel: blocks [0,16384) = RoPE on Q,K; blocks [16384,17408) =
// transpose V (cols 4096..6143 of QKV, ld 6144) -> VT[d][s] (ld 2048).
// ---------------------------------------------------------------------------
__global__ __launch_bounds__(256) void rope_trans(
    u16* __restrict__ qkv, const float* __restrict__ cs,
    const float* __restrict__ sn, u16* __restrict__ vt) {
  __shared__ u16 tile[64][68];
  const int bx = blockIdx.x;
  if (bx < 16384) {
    const int isK = bx >> 13;                  // 0 = Q, 1 = K
    int idx = (bx & 8191) * 256 + threadIdx.x;
    int p = idx & 63;
    int h = (idx >> 6) & 15;
    int s = idx >> 10;
    float c  = cs[(s << 6) | p];
    float si = sn[(s << 6) | p];
    float scale = isK ? 1.0f : 0.12751743f;    // log2(e)/sqrt(128)
    size_t off = (size_t)s * 6144 + (isK ? 2048 : 0) + (h << 7) + (p << 1);
    ushortx2 eo = *(ushortx2*)(qkv + off);
    float e = bf2f(eo.x), o = bf2f(eo.y);
    ushortx2 r;
    r.x = f2bf((e * c - o * si) * scale);
    r.y = f2bf((e * si + o * c) * scale);
    *(ushortx2*)(qkv + off) = r;
  } else {
    const int b = bx - 16384;
    const u16* src = qkv + 4096;
    const int d0 = (b & 31) << 6;
    const int s0 = (b >> 5) << 6;
    const int tx = (threadIdx.x & 15) << 2;
    const int ty = threadIdx.x >> 4;
#pragma unroll
    for (int rr = 0; rr < 64; rr += 16) {
      ushortx4 v = *(const ushortx4*)(src + (size_t)(s0 + ty + rr) * 6144 + d0 + tx);
      *(ushortx4*)&tile[ty + rr][tx] = v;
    }
    __syncthreads();
#pragma unroll
    for (int rr = 0; rr < 64; rr += 16) {
      int r = ty + rr;
      ushortx4 o;
      o.x = tile[tx + 0][r]; o.y = tile[tx + 1][r];
      o.z = tile[tx + 2][r]; o.w = tile[tx + 3][r];
      *(ushortx4*)(vt + (size_t)(d0 + r) * 2048 + s0 + tx) = o;
    }
  }
}

// ---------------------------------------------------------------------------
// Flash attention v7 (unchanged): 256 pair-blocks, 512 threads, 144 KiB LDS
// forces 1 block/CU; complementary q-tile pair per block = exactly 17
// iterations per CU; double-buffered K/V, 2 barriers/iter, counted vmcnt.
// ---------------------------------------------------------------------------
__global__ __launch_bounds__(512, 1) void flash_attn(
    const u16* __restrict__ QKVp, const u16* __restrict__ VTp,
    u16* __restrict__ ATp) {
  const int bid = (int)blockIdx.x;              // 256 blocks
  const int h   = bid & 15;
  const int g   = bid >> 4;                     // 0..15

  __shared__ __align__(16) u16 Ks[2][128][128]; // 64 KB
  __shared__ __align__(16) u16 Vs[2][128][128]; // 64 KB
  __shared__ __align__(16) u16 Ps[64][128];     // 16 KB

  const int t = threadIdx.x;
  const int lane = t & 63;
  const int wave = t >> 6;                      // 0..7
  const int quad = lane >> 4;
  const int mrow = lane & 15;
  const int sw   = mrow & 7;
  const int wmS = (wave & 1) << 5;
  const int wnS = (wave >> 1) << 5;
  const int wmV = (wave >> 1) << 5;
  const int wnP = (wave & 1) << 5;

  const int r4  = lane >> 4;
  const int seg = lane & 15;
  const int c0 = ((seg ^ r4) << 3);
  const int c4 = ((seg ^ (r4 + 4)) << 3);

  const u16* kbase = QKVp + 2048 + (h << 7);
  const u16* vbase = VTp + (size_t)(h << 7) * 2048;

#define STAGE_K(nb, kt)                                                        \
  do {                                                                         \
    int rr0_ = wave << 4;                                                      \
    _Pragma("unroll") for (int ii_ = 0; ii_ < 4; ii_++) {                      \
      int rr_ = rr0_ + (ii_ << 2);                                             \
      GLOAD_LDS16(kbase + (size_t)(((kt) << 7) + rr_ + r4) * 6144 +            \
                      ((ii_ & 1) ? c4 : c0),                                   \
                  &Ks[nb][rr_][0]);                                            \
    }                                                                          \
  } while (0)
#define STAGE_V(nb, kt)                                                        \
  do {                                                                         \
    int rr0_ = wave << 4;                                                      \
    _Pragma("unroll") for (int ii_ = 0; ii_ < 4; ii_++) {                      \
      int rr_ = rr0_ + (ii_ << 2);                                             \
      GLOAD_LDS16(vbase + (size_t)(rr_ + r4) * 2048 + ((kt) << 7) +            \
                      ((ii_ & 1) ? c4 : c0),                                   \
                  &Vs[nb][rr_][0]);                                            \
    }                                                                          \
  } while (0)

  const short8 ones = {0x3F80, 0x3F80, 0x3F80, 0x3F80,
                       0x3F80, 0x3F80, 0x3F80, 0x3F80};   // bf16 1.0 x8
  const float C2 = 23.083120654223414f;         // 16*log2(e)

  for (int pass = 0; pass < 2; pass++) {
    const int qsub  = pass ? g : 31 - g;        // heavy tile first
    const int q0    = qsub << 6;
    const int ktmax = qsub >> 1;
    const u16* qbase = QKVp + (size_t)q0 * 6144 + (h << 7);

    short8 aq[2][4];
#pragma unroll
    for (int i = 0; i < 2; i++)
#pragma unroll
      for (int kk = 0; kk < 4; kk++)
        aq[i][kk] = *(const short8*)(qbase +
                        (size_t)(wmS + (i << 4) + mrow) * 6144 +
                        (kk << 5) + (quad << 3));

    floatx4 Oa[2][2] = {};
    floatx4 Oa1[2] = {};

    STAGE_K(0, 0);
    STAGE_V(0, 0);
    WAITV(4);
    BAR;

    for (int kt = 0; kt <= ktmax; kt++) {
      const int b = kt & 1, nb = b ^ 1;

      floatx4 sa[2][2] = {};
#pragma unroll
      for (int kk = 0; kk < 4; kk++) {
        short8 bk[2];
#pragma unroll
        for (int j = 0; j < 2; j++)
          bk[j] = *(const short8*)&Ks[b][wnS + (j << 4) + mrow]
                      [(((kk << 2) | quad) ^ sw) << 3];
        __builtin_amdgcn_s_setprio(1);
#pragma unroll
        for (int i = 0; i < 2; i++)
#pragma unroll
          for (int j = 0; j < 2; j++)
            sa[i][j] = __builtin_amdgcn_mfma_f32_16x16x32_bf16(
                aq[i][kk], bk[j], sa[i][j], 0, 0, 0);
        __builtin_amdgcn_s_setprio(0);
      }

      if (kt < ktmax) {
        STAGE_K(nb, kt + 1);
        STAGE_V(nb, kt + 1);
      }

      if (kt == ktmax) {
#pragma unroll
        for (int i = 0; i < 2; i++)
#pragma unroll
          for (int j = 0; j < 2; j++)
#pragma unroll
            for (int r = 0; r < 4; r++) {
              int ql = q0 + wmS + (i << 4) + (quad << 2) + r;
              int sl = (kt << 7) + wnS + (j << 4) + mrow;
              if (sl > ql) sa[i][j][r] = -1e30f;
            }
      }
#pragma unroll
      for (int i = 0; i < 2; i++)
#pragma unroll
        for (int j = 0; j < 2; j++)
#pragma unroll
          for (int r = 0; r < 4; r++) {
            int row = wmS + (i << 4) + (quad << 2) + r;
            int col = wnS + (j << 4) + mrow;
            Ps[row][((((col >> 3) ^ (row & 7)) << 3) | (col & 7))] =
                f2bf(EXP2F(sa[i][j][r] - C2));
          }
      WAITL;
      if (kt < ktmax) WAITV(8);
      else            WAITV(0);
      BAR;  // B1: Ps visible + V(kt) resident

#pragma unroll
      for (int kk = 0; kk < 4; kk++) {
        short8 av[2], bp[2];
#pragma unroll
        for (int i = 0; i < 2; i++)
          av[i] = *(const short8*)&Vs[b][wmV + (i << 4) + mrow]
                      [(((kk << 2) | quad) ^ sw) << 3];
#pragma unroll
        for (int j = 0; j < 2; j++)
          bp[j] = *(const short8*)&Ps[wnP + (j << 4) + mrow]
                      [(((kk << 2) | quad) ^ sw) << 3];
        __builtin_amdgcn_s_setprio(1);
#pragma unroll
        for (int i = 0; i < 2; i++)
#pragma unroll
          for (int j = 0; j < 2; j++)
            Oa[i][j] = __builtin_amdgcn_mfma_f32_16x16x32_bf16(
                av[i], bp[j], Oa[i][j], 0, 0, 0);
#pragma unroll
        for (int j = 0; j < 2; j++)
          Oa1[j] = __builtin_amdgcn_mfma_f32_16x16x32_bf16(
              ones, bp[j], Oa1[j], 0, 0, 0);
        __builtin_amdgcn_s_setprio(0);
      }
      if (kt < ktmax) WAITV(4);
      BAR;  // B2
    }

    float linv[2];
#pragma unroll
    for (int j = 0; j < 2; j++) linv[j] = 1.f / Oa1[j][0];
#pragma unroll
    for (int i = 0; i < 2; i++) {
      int drow = (h << 7) + wmV + (i << 4) + (quad << 2);
#pragma unroll
      for (int j = 0; j < 2; j++) {
        int col = q0 + wnP + (j << 4) + mrow;
#pragma unroll
        for (int r = 0; r < 4; r++)
          ATp[(size_t)(drow + r) * 2048 + col] = f2bf(Oa[i][j][r] * linv[j]);
      }
    }
  }
#undef STAGE_K
#undef STAGE_V
}

// ---------------------------------------------------------------------------
// Orchestration:
//   QKV = BT256x192(x, [wq;wk;wv]); rope(Q,K) + VT = transpose(V) [merged];
//   AT  = flash_attn (256 pair-blocks, 1/CU forced);
//   out = gemm_out(AT, wo)  [128^2 tiles, 256 blocks, fp32 direct].
// ---------------------------------------------------------------------------
extern "C" void kernel_launch(void* const* d_in, const int* in_sizes, int n_in,
                              void* d_out, int out_size, void* d_ws, size_t ws_size,
                              hipStream_t stream) {
  const float* x  = (const float*)d_in[0];
  const float* fc = (const float*)d_in[1];
  const float* fs = (const float*)d_in[2];
  const float* wq = (const float*)d_in[4];
  const float* wk = (const float*)d_in[5];
  const float* wv = (const float*)d_in[6];
  const float* wo = (const float*)d_in[7];
  float* out = (float*)d_out;

  char* ws = (char*)d_ws;
  const size_t MB = 1024 * 1024;
  u16*   XB   = (u16*)(ws + 0 * MB);
  u16*   WQKV = (u16*)(ws + 8 * MB);     // [wq;wk;wv] 6144x2048
  u16*   WOb  = (u16*)(ws + 32 * MB);
  u16*   QKV  = (u16*)(ws + 40 * MB);    // [s][6144]
  u16*   VT   = (u16*)(ws + 64 * MB);    // [d][s]
  u16*   AT   = (u16*)(ws + 72 * MB);    // [(h*128+d)][q]

  dim3 blk(256);
  cvt_all<<<dim3(4096, 5), blk, 0, stream>>>(
      (const floatx4*)x, (const floatx4*)wq, (const floatx4*)wk,
      (const floatx4*)wv, (const floatx4*)wo,
      (ushortx4*)XB, (ushortx4*)WQKV, (ushortx4*)WOb);

  // fused QKV projection: M=2048, N=6144, K=2048 — 256x192 tiles,
  // 8 x 32 = 256 blocks (exactly 1/CU), 512 threads.
  gemm256_bt<<<dim3(256), dim3(512), 0, stream>>>(XB, WQKV, QKV,
                                                  6144, 2048, 2048, 2048, 6144);

  // rope(Q,K) [16384 blocks] + transpose V -> VT [1024 blocks], one launch
  rope_trans<<<dim3(17408), blk, 0, stream>>>(QKV, fc, fs, VT);

  // 256 pair-blocks, 512 threads, 144 KiB LDS (forces 1 block/CU)
  flash_attn<<<dim3(256), dim3(512), 0, stream>>>(QKV, VT, AT);

  // final projection: out[r][j] = sum_q AT[r][q] * wo[j][q], fp32 direct
  gemm_out<<<dim3(256), blk, 0, stream>>>(AT, WOb, out);
}

// Round 10
// 263.524 us; speedup vs baseline: 1.0371x; 1.0371x over previous
//
#include <hip/hip_runtime.h>

typedef unsigned short u16;
typedef unsigned int   u32;
typedef short  short8   __attribute__((ext_vector_type(8)));
typedef float  floatx4  __attribute__((ext_vector_type(4)));
typedef u16    ushortx2 __attribute__((ext_vector_type(2)));
typedef u16    ushortx4 __attribute__((ext_vector_type(4)));

__device__ __forceinline__ float bf2f(u16 u) {
  union { u32 i; float f; } v; v.i = ((u32)u) << 16; return v.f;
}
__device__ __forceinline__ u16 f2bf(float x) {
  union { float f; u32 i; } v; v.f = x;
  u32 r = v.i + 0x7FFFu + ((v.i >> 16) & 1u);   // round-to-nearest-even
  return (u16)(r >> 16);
}

#if __has_builtin(__builtin_amdgcn_exp2f)
#define EXP2F(x) __builtin_amdgcn_exp2f(x)
#else
#define EXP2F(x) __exp2f(x)
#endif

// async global->LDS, 16B per lane; LDS dest = wave-uniform base + lane*16
#define GLOAD_LDS16(gptr, lptr)                                                   \
  __builtin_amdgcn_global_load_lds(                                               \
      (const __attribute__((address_space(1))) void*)(gptr),                      \
      (__attribute__((address_space(3))) void*)(lptr), 16, 0, 0)

#define WAITV(n) asm volatile("s_waitcnt vmcnt(" #n ")" ::: "memory")
#define WAITL    asm volatile("s_waitcnt lgkmcnt(0)" ::: "memory")
#define BAR      __builtin_amdgcn_s_barrier()

// ---------------------------------------------------------------------------
// fp32 -> bf16 bulk convert, all 5 tensors in one launch (blockIdx.y selects).
// wq/wk/wv land contiguously so the QKV projection is one N=6144 GEMM.
// ---------------------------------------------------------------------------
__global__ __launch_bounds__(256) void cvt_all(
    const floatx4* __restrict__ x,  const floatx4* __restrict__ wq,
    const floatx4* __restrict__ wk, const floatx4* __restrict__ wv,
    const floatx4* __restrict__ wo,
    ushortx4* __restrict__ xb, ushortx4* __restrict__ wqkv,
    ushortx4* __restrict__ wob) {
  int i = blockIdx.x * 256 + threadIdx.x;
  const floatx4* in; ushortx4* out;
  switch (blockIdx.y) {
    case 0:  in = x;  out = xb; break;
    case 1:  in = wq; out = wqkv; break;
    case 2:  in = wk; out = wqkv + (size_t)1048576; break;   // 2048*2048/4
    case 3:  in = wv; out = wqkv + (size_t)2097152; break;
    default: in = wo; out = wob; break;
  }
  floatx4 v = in[i];
  ushortx4 o;
  o.x = f2bf(v.x); o.y = f2bf(v.y); o.z = f2bf(v.z); o.w = f2bf(v.w);
  out[i] = o;
}

// ---------------------------------------------------------------------------
// 256x192 8-wave BT-GEMM, BK=64, 3-phase K-loop (16 MFMA/phase), counted
// vmcnt.  C[m][n] = sum_k A[m][k]*B[n][k], C written bf16.
// R10: EXACT R3 form restored (53.5 us, 963 TF on the QKV shape).  Two
// refinement attempts regressed and are reverted for good:
//  - R8 cross-phase register pipelining: +32 VGPR, scratch spill, -4%.
//  - R9 burst-issue staging (all 7 gloads at P1): P1 issue-port pressure
//    delayed its own ds_read+MFMA stream, -6%.
// The spread staging/wait placement below is the measured optimum for this
// 3-phase structure; remaining stall is structural barrier skew.
// ---------------------------------------------------------------------------
__global__ __launch_bounds__(512, 2) void gemm256_bt(
    const u16* __restrict__ A, const u16* __restrict__ B, u16* __restrict__ C,
    int N, int K, int lda, int ldb, int ldc) {
  // bijective XCD swizzle (gridDim.x % 8 == 0)
  const int cpx = gridDim.x >> 3;
  const int wg = ((int)blockIdx.x & 7) * cpx + ((int)blockIdx.x >> 3);
  const int ntn = N / 192;
  const int m0 = (wg / ntn) << 8;
  const int n0 = (wg % ntn) * 192;

  __shared__ __align__(16) u16 As[2][256][64];
  __shared__ __align__(16) u16 Bs[2][192][64];

  const int t = threadIdx.x;
  const int lane = t & 63;
  const int wave = t >> 6;
  const int wr = wave >> 2;          // 0..1
  const int wc = wave & 3;           // 0..3
  const int quad = lane >> 4;
  const int mrow = lane & 15;
  const int sw = mrow & 7;

  // staging: per gload, wave writes 1 KiB = 8 rows x 8 segs; global col-seg
  // pre-swizzled so a linear LDS write realizes the seg-XOR layout.
  const int srow = lane >> 3;                    // 0..7
  const int gso  = ((lane & 7) ^ srow) << 3;     // u16 col offset

  const u16* gA = A + (size_t)(m0 + (wave << 3) + srow) * lda + gso;
  const u16* gB = B + (size_t)(n0 + (wave << 3) + srow) * ldb + gso;

  floatx4 acc[8][3] = {};
  short8 afr[4][2], bfr[3][2];

  const int NT = K >> 6;                         // K-tiles (NT >= 2)

#define ST_A(nb, h, kt)                                                        \
  do {                                                                         \
    GLOAD_LDS16(gA + (size_t)((h) * 128) * lda + ((kt) << 6),                  \
                &As[nb][(h) * 128 + (wave << 3)][0]);                          \
    GLOAD_LDS16(gA + (size_t)((h) * 128 + 64) * lda + ((kt) << 6),             \
                &As[nb][(h) * 128 + 64 + (wave << 3)][0]);                     \
  } while (0)
#define ST_B1(nb, c, kt)                                                       \
  do {                                                                         \
    GLOAD_LDS16(gB + (size_t)((c) * 64) * ldb + ((kt) << 6),                   \
                &Bs[nb][(c) * 64 + (wave << 3)][0]);                           \
  } while (0)

  // A frags i0..3 from rows base_row + i*16 + mrow of As[bf]
#define LDA4(bf, base_row)                                                     \
  do {                                                                         \
    _Pragma("unroll") for (int i_ = 0; i_ < 4; i_++)                           \
      _Pragma("unroll") for (int kk_ = 0; kk_ < 2; kk_++)                      \
        afr[i_][kk_] = *(const short8*)&As[bf][(base_row) + (i_ << 4) + mrow]  \
                            [(((kk_ << 2) | quad) ^ sw) << 3];                 \
  } while (0)
  // B frag j from rows j*64 + wc*16 + mrow of Bs[bf]
#define LDB1(bf, j)                                                            \
  do {                                                                         \
    _Pragma("unroll") for (int kk_ = 0; kk_ < 2; kk_++)                        \
      bfr[j][kk_] = *(const short8*)&Bs[bf][(j) * 64 + (wc << 4) + mrow]       \
          [(((kk_ << 2) | quad) ^ sw) << 3];                                   \
  } while (0)
  // one sub-block: 4 i x 1 j x 2 kk = 8 MFMA (afr holds the i-set for ilo)
#define MMQ8(ilo, j)                                                           \
  do {                                                                         \
    __builtin_amdgcn_s_setprio(1);                                             \
    _Pragma("unroll") for (int kk_ = 0; kk_ < 2; kk_++)                        \
      _Pragma("unroll") for (int i_ = 0; i_ < 4; i_++)                         \
        acc[(ilo) + i_][j] = __builtin_amdgcn_mfma_f32_16x16x32_bf16(          \
            afr[i_][kk_], bfr[j][kk_], acc[(ilo) + i_][j], 0, 0, 0);           \
    __builtin_amdgcn_s_setprio(0);                                             \
  } while (0)

  // prologue: stage tile 0 in FIFO order g1..g7
  ST_A(0, 0, 0); ST_B1(0, 0, 0); ST_B1(0, 1, 0); ST_B1(0, 2, 0); ST_A(0, 1, 0);
  WAITV(3);                                    // g1..g4 resident for P1
  BAR;

  for (int kt = 0; kt < NT - 1; kt++) {
    const int bf = kt & 1, nb = bf ^ 1;
    // ---- P1: reads g1..g4(kt); issues g1..g3(kt+1) ----
    LDA4(bf, (wr << 6));                       // A-h0 rows
    LDB1(bf, 0);                               // B-c0
    LDB1(bf, 1);                               // B-c1
    ST_A(nb, 0, kt + 1);                       // g1',g2'
    ST_B1(nb, 0, kt + 1);                      // g3'
    WAITV(3);                                  // kt g5..g7 resident (P2 reads)
    BAR;
    MMQ8(0, 0);
    MMQ8(0, 1);
    // ---- P2: reads g5..g7(kt); issues g4,g5(kt+1) ----
    LDB1(bf, 2);                               // B-c2
    ST_B1(nb, 1, kt + 1);                      // g4'
    ST_B1(nb, 2, kt + 1);                      // g5'
    BAR;                                       // no wait: P3 reads nothing
    MMQ8(0, 2);
    LDA4(bf, 128 + (wr << 6));                 // A-h1 (g6,g7 resident via P1 wait)
    MMQ8(4, 0);
    // ---- P3: register-only; issues g6,g7(kt+1) ----
    ST_A(nb, 1, kt + 1);                       // g6',g7'
    WAITV(3);                                  // kt+1 g1..g4 resident (next P1)
    BAR;
    MMQ8(4, 1);
    MMQ8(4, 2);
  }
  {                                            // last tile, no staging
    const int bf = (NT - 1) & 1;
    LDA4(bf, (wr << 6));
    LDB1(bf, 0);
    LDB1(bf, 1);
    WAITV(0);                                  // g5..g7 resident
    BAR;
    MMQ8(0, 0);
    MMQ8(0, 1);
    LDB1(bf, 2);
    BAR;
    MMQ8(0, 2);
    LDA4(bf, 128 + (wr << 6));
    MMQ8(4, 0);
    BAR;
    MMQ8(4, 1);
    MMQ8(4, 2);
  }

  // epilogue. C/D layout: col = lane&15, row = quad*4 + reg
#pragma unroll
  for (int i = 0; i < 8; i++) {
    int row0 = m0 + ((i >= 4) ? 128 : 0) + (wr << 6) + ((i & 3) << 4) + (quad << 2);
#pragma unroll
    for (int j = 0; j < 3; j++) {
      int col = n0 + j * 64 + (wc << 4) + mrow;
#pragma unroll
      for (int r = 0; r < 4; r++)
        C[(size_t)(row0 + r) * ldc + col] = f2bf(acc[i][j][r]);
    }
  }
#undef ST_A
#undef ST_B1
#undef LDA4
#undef LDB1
#undef MMQ8
}

// ---------------------------------------------------------------------------
// Output projection: out[m][n] = sum_k AT[m][k]*WOb[n][k], fp32 out direct.
// 128x128 tile, 256 blocks (full fill), 2 blocks/CU, 2-phase counted vmcnt.
// R10: EXACT R5 form restored (R9's burst-issue variant reverted with the
// QKV kernel's — same regression mechanism).
// ---------------------------------------------------------------------------
__global__ __launch_bounds__(256, 2) void gemm_out(
    const u16* __restrict__ A, const u16* __restrict__ B,
    float* __restrict__ C) {
  // bijective XCD swizzle over 256 blocks
  const int wg = ((int)blockIdx.x & 7) * 32 + ((int)blockIdx.x >> 3);
  const int m0 = (wg >> 4) << 7;
  const int n0 = (wg & 15) << 7;

  __shared__ __align__(16) u16 As[2][128][64];
  __shared__ __align__(16) u16 Bs[2][128][64];

  const int t = threadIdx.x;
  const int lane = t & 63;
  const int wave = t >> 6;           // 0..3
  const int wr = wave >> 1;          // 0..1
  const int wc = wave & 1;           // 0..1
  const int quad = lane >> 4;
  const int mrow = lane & 15;
  const int sw = mrow & 7;

  const int srow = lane >> 3;                    // 0..7
  const int gso  = ((lane & 7) ^ srow) << 3;     // pre-swizzled col seg

  const u16* gA = A + (size_t)(m0 + (wave << 3) + srow) * 2048 + gso;
  const u16* gB = B + (size_t)(n0 + (wave << 3) + srow) * 2048 + gso;

  floatx4 acc[4][4] = {};
  short8 afr[4][2], bfr[4][2];

  const int NT = 32;                             // 2048/64

#define OST_A(nb, p, kt)                                                       \
  GLOAD_LDS16(gA + (size_t)((p) * 32) * 2048 + ((kt) << 6),                    \
              &As[nb][(p) * 32 + (wave << 3)][0])
#define OST_B(nb, p, kt)                                                       \
  GLOAD_LDS16(gB + (size_t)((p) * 32) * 2048 + ((kt) << 6),                    \
              &Bs[nb][(p) * 32 + (wave << 3)][0])

#define OLDA(bf)                                                               \
  do {                                                                         \
    _Pragma("unroll") for (int i_ = 0; i_ < 4; i_++)                           \
      _Pragma("unroll") for (int kk_ = 0; kk_ < 2; kk_++)                      \
        afr[i_][kk_] = *(const short8*)&As[bf][(wr << 6) + (i_ << 4) + mrow]   \
                            [(((kk_ << 2) | quad) ^ sw) << 3];                 \
  } while (0)
#define OLDB2(bf, jlo)                                                         \
  do {                                                                         \
    _Pragma("unroll") for (int j_ = 0; j_ < 2; j_++)                           \
      _Pragma("unroll") for (int kk_ = 0; kk_ < 2; kk_++)                      \
        bfr[(jlo) + j_][kk_] =                                                 \
            *(const short8*)&Bs[bf][(wc << 6) + (((jlo) + j_) << 4) + mrow]    \
                [(((kk_ << 2) | quad) ^ sw) << 3];                             \
  } while (0)
#define OMM16(jlo)                                                             \
  do {                                                                         \
    __builtin_amdgcn_s_setprio(1);                                             \
    _Pragma("unroll") for (int kk_ = 0; kk_ < 2; kk_++)                        \
      _Pragma("unroll") for (int i_ = 0; i_ < 4; i_++)                         \
        _Pragma("unroll") for (int j_ = 0; j_ < 2; j_++)                       \
          acc[i_][(jlo) + j_] = __builtin_amdgcn_mfma_f32_16x16x32_bf16(       \
              afr[i_][kk_], bfr[(jlo) + j_][kk_], acc[i_][(jlo) + j_], 0, 0, 0);\
    __builtin_amdgcn_s_setprio(0);                                             \
  } while (0)

  // prologue: FIFO g1..g8 = A0,A1,A2,A3,B0,B2,B1,B3
  OST_A(0, 0, 0); OST_A(0, 1, 0); OST_A(0, 2, 0); OST_A(0, 3, 0);
  OST_B(0, 0, 0); OST_B(0, 2, 0); OST_B(0, 1, 0); OST_B(0, 3, 0);
  WAITV(2);                                    // g1..g6 resident for P1
  BAR;

  for (int kt = 0; kt < NT - 1; kt++) {
    const int bf = kt & 1, nb = bf ^ 1;
    // ---- P1 ----
    OLDA(bf);
    OLDB2(bf, 0);
    OST_A(nb, 0, kt + 1); OST_A(nb, 1, kt + 1);
    OST_A(nb, 2, kt + 1); OST_A(nb, 3, kt + 1);
    OST_B(nb, 0, kt + 1); OST_B(nb, 2, kt + 1);
    WAITV(6);                                  // g7,g8(kt) resident
    BAR;
    OMM16(0);
    // ---- P2 ----
    OLDB2(bf, 2);
    OST_B(nb, 1, kt + 1); OST_B(nb, 3, kt + 1);
    WAITV(2);                                  // g1'..g6' resident (next P1)
    BAR;
    OMM16(2);
  }
  {                                            // last tile, no staging
    const int bf = (NT - 1) & 1;
    OLDA(bf);
    OLDB2(bf, 0);
    WAITV(0);                                  // g7,g8 resident
    BAR;
    OMM16(0);
    OLDB2(bf, 2);
    OMM16(2);
  }

  // epilogue: fp32 direct. C/D layout: col = lane&15, row = quad*4 + reg
#pragma unroll
  for (int i = 0; i < 4; i++) {
    int row0 = m0 + (wr << 6) + (i << 4) + (quad << 2);
#pragma unroll
    for (int j = 0; j < 4; j++) {
      int col = n0 + (wc << 6) + (j << 4) + mrow;
#pragma unroll
      for (int r = 0; r < 4; r++)
        C[(size_t)(row0 + r) * 2048 + col] = acc[i][j][r];
    }
  }
#undef OST_A
#undef OST_B
#undef OLDA
#undef OLDB2
#undef OMM16
}

// ---------------------------------------------------------------------------
// Merged aux kernel: blocks [0,16384) = RoPE on Q,K; blocks [16384,17408) =
// transpose V (cols 4096..6143 of QKV, ld 6144) -> VT[d][s] (ld 2048).
// ---------------------------------------------------------------------------
__global__ __launch_bounds__(256) void rope_trans(
    u16* __restrict__ qkv, const float* __restrict__ cs,
    const float* __restrict__ sn, u16* __restrict__ vt) {
  __shared__ u16 tile[64][68];
  const int bx = blockIdx.x;
  if (bx < 16384) {
    const int isK = bx >> 13;                  // 0 = Q, 1 = K
    int idx = (bx & 8191) * 256 + threadIdx.x;
    int p = idx & 63;
    int h = (idx >> 6) & 15;
    int s = idx >> 10;
    float c  = cs[(s << 6) | p];
    float si = sn[(s << 6) | p];
    float scale = isK ? 1.0f : 0.12751743f;    // log2(e)/sqrt(128)
    size_t off = (size_t)s * 6144 + (isK ? 2048 : 0) + (h << 7) + (p << 1);
    ushortx2 eo = *(ushortx2*)(qkv + off);
    float e = bf2f(eo.x), o = bf2f(eo.y);
    ushortx2 r;
    r.x = f2bf((e * c - o * si) * scale);
    r.y = f2bf((e * si + o * c) * scale);
    *(ushortx2*)(qkv + off) = r;
  } else {
    const int b = bx - 16384;
    const u16* src = qkv + 4096;
    const int d0 = (b & 31) << 6;
    const int s0 = (b >> 5) << 6;
    const int tx = (threadIdx.x & 15) << 2;
    const int ty = threadIdx.x >> 4;
#pragma unroll
    for (int rr = 0; rr < 64; rr += 16) {
      ushortx4 v = *(const ushortx4*)(src + (size_t)(s0 + ty + rr) * 6144 + d0 + tx);
      *(ushortx4*)&tile[ty + rr][tx] = v;
    }
    __syncthreads();
#pragma unroll
    for (int rr = 0; rr < 64; rr += 16) {
      int r = ty + rr;
      ushortx4 o;
      o.x = tile[tx + 0][r]; o.y = tile[tx + 1][r];
      o.z = tile[tx + 2][r]; o.w = tile[tx + 3][r];
      *(ushortx4*)(vt + (size_t)(d0 + r) * 2048 + s0 + tx) = o;
    }
  }
}

// ---------------------------------------------------------------------------
// Flash attention v6 (R10: restored from the best-measured R6 config).
// 512 blocks, 2 blocks/CU; complementary-pair block mapping; K(t+1) staged
// at B3 under PV, V(t+1) at B1 under QK^T, counted vmcnt(8).
// ---------------------------------------------------------------------------
__global__ __launch_bounds__(256, 2) void flash_attn(
    const u16* __restrict__ QKVp, const u16* __restrict__ VTp,
    u16* __restrict__ ATp) {
  const int bid  = (int)blockIdx.x;
  const int g    = (bid & 255) >> 4;            // 0..15
  const int h    = bid & 15;
  const int qsub = (bid >> 8) ? g : 31 - g;     // complementary pairing
  const int q0 = qsub << 6;
  const int ktmax = qsub >> 1;

  __shared__ __align__(16) u16 Ks[128][128];    // K tile [s][d]   (32 KB)
  __shared__ __align__(16) u16 Vs[128][128];    // VT tile [d][s]  (32 KB)
  __shared__ __align__(16) u16 Ps[64][128];     // P tile  [q][s]  (16 KB)

  const int t = threadIdx.x;
  const int lane = t & 63;
  const int wave = t >> 6;
  const int quad = lane >> 4;
  const int mrow = lane & 15;
  const int sw   = mrow & 7;
  const int wmS = (wave & 1) << 5;
  const int wnS = (wave >> 1) << 6;
  const int wmV = (wave >> 1) << 6;
  const int wnP = (wave & 1) << 5;

  const int r4  = lane >> 4;
  const int seg = lane & 15;
  const int c0 = ((seg ^ r4) << 3);
  const int c4 = ((seg ^ (r4 + 4)) << 3);

  const u16* qbase = QKVp + (size_t)q0 * 6144 + (h << 7);
  const u16* kbase = QKVp + 2048 + (h << 7);
  const u16* vbase = VTp + (size_t)(h << 7) * 2048;

#define STAGE_K(kt)                                                            \
  do {                                                                         \
    int rr0_ = wave << 5;                                                      \
    _Pragma("unroll") for (int ii_ = 0; ii_ < 8; ii_++) {                      \
      int rr_ = rr0_ + (ii_ << 2);                                             \
      GLOAD_LDS16(kbase + (size_t)(((kt) << 7) + rr_ + r4) * 6144 +            \
                      ((ii_ & 1) ? c4 : c0),                                   \
                  &Ks[rr_][0]);                                                \
    }                                                                          \
  } while (0)
#define STAGE_V(kt)                                                            \
  do {                                                                         \
    int rr0_ = wave << 5;                                                      \
    _Pragma("unroll") for (int ii_ = 0; ii_ < 8; ii_++) {                      \
      int rr_ = rr0_ + (ii_ << 2);                                             \
      GLOAD_LDS16(vbase + (size_t)(rr_ + r4) * 2048 + ((kt) << 7) +            \
                      ((ii_ & 1) ? c4 : c0),                                   \
                  &Vs[rr_][0]);                                                \
    }                                                                          \
  } while (0)

  short8 aq[2][4];
#pragma unroll
  for (int i = 0; i < 2; i++)
#pragma unroll
    for (int kk = 0; kk < 4; kk++)
      aq[i][kk] = *(const short8*)(qbase + (size_t)(wmS + (i << 4) + mrow) * 6144 +
                                   (kk << 5) + (quad << 3));

  const short8 ones = {0x3F80, 0x3F80, 0x3F80, 0x3F80,
                       0x3F80, 0x3F80, 0x3F80, 0x3F80};   // bf16 1.0 x8

  floatx4 Oa[4][2] = {};                        // O^T tile (d x q)
  floatx4 Oa1[2] = {};                          // row-sums l

  const float C2 = 23.083120654223414f;         // 16*log2(e)

  STAGE_K(0);
  STAGE_V(0);
  WAITV(8);                                     // K(0) resident (this wave)
  BAR;                                          // K(0) resident (all waves)

  for (int kt = 0; kt <= ktmax; kt++) {
    // ---- S-phase: S' = Q'.K^T (V(kt) gloads still in flight) ----
    floatx4 sa[2][4] = {};
#pragma unroll
    for (int kk = 0; kk < 4; kk++) {
      short8 bk[4];
#pragma unroll
      for (int j = 0; j < 4; j++)
        bk[j] = *(const short8*)&Ks[wnS + (j << 4) + mrow][(((kk << 2) | quad) ^ sw) << 3];
      __builtin_amdgcn_s_setprio(1);
#pragma unroll
      for (int i = 0; i < 2; i++)
#pragma unroll
        for (int j = 0; j < 4; j++)
          sa[i][j] = __builtin_amdgcn_mfma_f32_16x16x32_bf16(aq[i][kk], bk[j], sa[i][j], 0, 0, 0);
      __builtin_amdgcn_s_setprio(0);
    }
    if (kt == ktmax) {                          // causal mask on diagonal tile
#pragma unroll
      for (int i = 0; i < 2; i++)
#pragma unroll
        for (int j = 0; j < 4; j++)
#pragma unroll
          for (int r = 0; r < 4; r++) {
            int ql = q0 + wmS + (i << 4) + (quad << 2) + r;
            int sl = (kt << 7) + wnS + (j << 4) + mrow;
            if (sl > ql) sa[i][j][r] = -1e30f;  // exp2 -> exact 0
          }
    }
#pragma unroll
    for (int i = 0; i < 2; i++)
#pragma unroll
      for (int j = 0; j < 4; j++)
#pragma unroll
        for (int r = 0; r < 4; r++) {
          int row = wmS + (i << 4) + (quad << 2) + r;
          int col = wnS + (j << 4) + mrow;
          Ps[row][((((col >> 3) ^ (row & 7)) << 3) | (col & 7))] =
              f2bf(EXP2F(sa[i][j][r] - C2));
        }
    WAITV(0);                                   // V(kt) resident (this wave)
    WAITL;                                      // Ps write + Ks reads retired
    BAR;  // B3: Ps visible, Vs resident, all waves' Ks reads done

    if (kt < ktmax) STAGE_K(kt + 1);            // lands under PV's MFMAs

    // ---- PV: O^T[d][q] += VT.P^T ; l[q] += ones.P^T ----
#pragma unroll
    for (int kk = 0; kk < 4; kk++) {
      short8 av[4], bp[2];
#pragma unroll
      for (int i = 0; i < 4; i++)
        av[i] = *(const short8*)&Vs[wmV + (i << 4) + mrow][(((kk << 2) | quad) ^ sw) << 3];
#pragma unroll
      for (int j = 0; j < 2; j++)
        bp[j] = *(const short8*)&Ps[wnP + (j << 4) + mrow][(((kk << 2) | quad) ^ sw) << 3];
      __builtin_amdgcn_s_setprio(1);
#pragma unroll
      for (int i = 0; i < 4; i++)
#pragma unroll
        for (int j = 0; j < 2; j++)
          Oa[i][j] = __builtin_amdgcn_mfma_f32_16x16x32_bf16(av[i], bp[j], Oa[i][j], 0, 0, 0);
#pragma unroll
      for (int j = 0; j < 2; j++)
        Oa1[j] = __builtin_amdgcn_mfma_f32_16x16x32_bf16(ones, bp[j], Oa1[j], 0, 0, 0);
      __builtin_amdgcn_s_setprio(0);
    }
    WAITL;                                      // Vs/Ps reads retired
    BAR;  // B1: all waves done reading Vs/Ps

    if (kt < ktmax) STAGE_V(kt + 1);            // lands under next QK^T
    WAITV(8);                                   // K(kt+1) resident (this wave)
    BAR;  // B2: K(kt+1) resident (all waves)
  }
#undef STAGE_K
#undef STAGE_V

  // epilogue: AT[(h*128+d)][q0+q] = O/l, bf16
  float linv[2];
#pragma unroll
  for (int j = 0; j < 2; j++) linv[j] = 1.f / Oa1[j][0];
#pragma unroll
  for (int i = 0; i < 4; i++) {
    int drow = (h << 7) + wmV + (i << 4) + (quad << 2);
#pragma unroll
    for (int j = 0; j < 2; j++) {
      int col = q0 + wnP + (j << 4) + mrow;
#pragma unroll
      for (int r = 0; r < 4; r++)
        ATp[(size_t)(drow + r) * 2048 + col] = f2bf(Oa[i][j][r] * linv[j]);
    }
  }
}

// ---------------------------------------------------------------------------
// Orchestration (best-measured R6 configuration):
//   QKV = BT256x192(x, [wq;wk;wv]); rope(Q,K) + VT = transpose(V) [merged];
//   AT  = flash_attn (512 blocks, complementary-pair balanced);
//   out = gemm_out(AT, wo)  [128^2 tiles, 256 blocks, fp32 direct].
// ---------------------------------------------------------------------------
extern "C" void kernel_launch(void* const* d_in, const int* in_sizes, int n_in,
                              void* d_out, int out_size, void* d_ws, size_t ws_size,
                              hipStream_t stream) {
  const float* x  = (const float*)d_in[0];
  const float* fc = (const float*)d_in[1];
  const float* fs = (const float*)d_in[2];
  const float* wq = (const float*)d_in[4];
  const float* wk = (const float*)d_in[5];
  const float* wv = (const float*)d_in[6];
  const float* wo = (const float*)d_in[7];
  float* out = (float*)d_out;

  char* ws = (char*)d_ws;
  const size_t MB = 1024 * 1024;
  u16*   XB   = (u16*)(ws + 0 * MB);
  u16*   WQKV = (u16*)(ws + 8 * MB);     // [wq;wk;wv] 6144x2048
  u16*   WOb  = (u16*)(ws + 32 * MB);
  u16*   QKV  = (u16*)(ws + 40 * MB);    // [s][6144]
  u16*   VT   = (u16*)(ws + 64 * MB);    // [d][s]
  u16*   AT   = (u16*)(ws + 72 * MB);    // [(h*128+d)][q]

  dim3 blk(256);
  cvt_all<<<dim3(4096, 5), blk, 0, stream>>>(
      (const floatx4*)x, (const floatx4*)wq, (const floatx4*)wk,
      (const floatx4*)wv, (const floatx4*)wo,
      (ushortx4*)XB, (ushortx4*)WQKV, (ushortx4*)WOb);

  // fused QKV projection: M=2048, N=6144, K=2048 — 256x192 tiles,
  // 8 x 32 = 256 blocks (exactly 1/CU), 512 threads.
  gemm256_bt<<<dim3(256), dim3(512), 0, stream>>>(XB, WQKV, QKV,
                                                  6144, 2048, 2048, 2048, 6144);

  // rope(Q,K) [16384 blocks] + transpose V -> VT [1024 blocks], one launch
  rope_trans<<<dim3(17408), blk, 0, stream>>>(QKV, fc, fs, VT);

  flash_attn<<<dim3(512), blk, 0, stream>>>(QKV, VT, AT);

  // final projection: out[r][j] = sum_q AT[r][q] * wo[j][q], fp32 direct
  gemm_out<<<dim3(256), blk, 0, stream>>>(AT, WOb, out);
}

// Round 11
// 262.526 us; speedup vs baseline: 1.0410x; 1.0038x over previous
//
#include <hip/hip_runtime.h>

typedef unsigned short u16;
typedef unsigned int   u32;
typedef short  short8   __attribute__((ext_vector_type(8)));
typedef float  floatx4  __attribute__((ext_vector_type(4)));
typedef u16    ushortx2 __attribute__((ext_vector_type(2)));
typedef u16    ushortx4 __attribute__((ext_vector_type(4)));

__device__ __forceinline__ float bf2f(u16 u) {
  union { u32 i; float f; } v; v.i = ((u32)u) << 16; return v.f;
}
__device__ __forceinline__ u16 f2bf(float x) {
  union { float f; u32 i; } v; v.f = x;
  u32 r = v.i + 0x7FFFu + ((v.i >> 16) & 1u);   // round-to-nearest-even
  return (u16)(r >> 16);
}

#if __has_builtin(__builtin_amdgcn_exp2f)
#define EXP2F(x) __builtin_amdgcn_exp2f(x)
#else
#define EXP2F(x) __exp2f(x)
#endif

// async global->LDS, 16B per lane; LDS dest = wave-uniform base + lane*16
#define GLOAD_LDS16(gptr, lptr)                                                   \
  __builtin_amdgcn_global_load_lds(                                               \
      (const __attribute__((address_space(1))) void*)(gptr),                      \
      (__attribute__((address_space(3))) void*)(lptr), 16, 0, 0)

#define WAITV(n) asm volatile("s_waitcnt vmcnt(" #n ")" ::: "memory")
#define WAITL    asm volatile("s_waitcnt lgkmcnt(0)" ::: "memory")
#define BAR      __builtin_amdgcn_s_barrier()

// ---------------------------------------------------------------------------
// fp32 -> bf16 bulk convert, all 5 tensors in one launch (blockIdx.y selects).
// wq/wk/wv land contiguously so the QKV projection is one N=6144 GEMM.
// ---------------------------------------------------------------------------
__global__ __launch_bounds__(256) void cvt_all(
    const floatx4* __restrict__ x,  const floatx4* __restrict__ wq,
    const floatx4* __restrict__ wk, const floatx4* __restrict__ wv,
    const floatx4* __restrict__ wo,
    ushortx4* __restrict__ xb, ushortx4* __restrict__ wqkv,
    ushortx4* __restrict__ wob) {
  int i = blockIdx.x * 256 + threadIdx.x;
  const floatx4* in; ushortx4* out;
  switch (blockIdx.y) {
    case 0:  in = x;  out = xb; break;
    case 1:  in = wq; out = wqkv; break;
    case 2:  in = wk; out = wqkv + (size_t)1048576; break;   // 2048*2048/4
    case 3:  in = wv; out = wqkv + (size_t)2097152; break;
    default: in = wo; out = wob; break;
  }
  floatx4 v = in[i];
  ushortx4 o;
  o.x = f2bf(v.x); o.y = f2bf(v.y); o.z = f2bf(v.z); o.w = f2bf(v.w);
  out[i] = o;
}

// ---------------------------------------------------------------------------
// 256x192 8-wave BT-GEMM, BK=64, 3-phase K-loop (16 MFMA/phase), counted
// vmcnt.  C[m][n] = sum_k A[m][k]*B[n][k], C written bf16.
// K-loop = EXACT R3 form (measured local optimum; R8 reg-pipelining and R9
// burst-issue staging both regressed and stay reverted).
//
// R11: RoPE FUSED INTO THE EPILOGUE.  Output cols <4096 are Q|K; rotation
// pairs (2p,2p+1) are adjacent cols = lanes (mrow, mrow^1) of the same wave
// -> partner value via __shfl_xor(v,1).  Both predicates (col<4096 Q/K,
// col<2048 Q-scale) are wave-uniform: boundaries are multiples of 64 and
// each j-chunk spans exactly 64 cols.  Rope applies to the fp32 accumulator
// BEFORE bf16 rounding (one rounding vs the old GEMM->bf16->rope->bf16 two)
// — values match reference at least as closely as the two-pass form.
// Q pre-scaled by log2(e)/sqrt(128) so flash's softmax is a single exp2.
// ---------------------------------------------------------------------------
__global__ __launch_bounds__(512, 2) void gemm256_bt(
    const u16* __restrict__ A, const u16* __restrict__ B, u16* __restrict__ C,
    int N, int K, int lda, int ldb, int ldc,
    const float* __restrict__ cs, const float* __restrict__ sn) {
  // bijective XCD swizzle (gridDim.x % 8 == 0)
  const int cpx = gridDim.x >> 3;
  const int wg = ((int)blockIdx.x & 7) * cpx + ((int)blockIdx.x >> 3);
  const int ntn = N / 192;
  const int m0 = (wg / ntn) << 8;
  const int n0 = (wg % ntn) * 192;

  __shared__ __align__(16) u16 As[2][256][64];
  __shared__ __align__(16) u16 Bs[2][192][64];

  const int t = threadIdx.x;
  const int lane = t & 63;
  const int wave = t >> 6;
  const int wr = wave >> 2;          // 0..1
  const int wc = wave & 3;           // 0..3
  const int quad = lane >> 4;
  const int mrow = lane & 15;
  const int sw = mrow & 7;

  // staging: per gload, wave writes 1 KiB = 8 rows x 8 segs; global col-seg
  // pre-swizzled so a linear LDS write realizes the seg-XOR layout.
  const int srow = lane >> 3;                    // 0..7
  const int gso  = ((lane & 7) ^ srow) << 3;     // u16 col offset

  const u16* gA = A + (size_t)(m0 + (wave << 3) + srow) * lda + gso;
  const u16* gB = B + (size_t)(n0 + (wave << 3) + srow) * ldb + gso;

  floatx4 acc[8][3] = {};
  short8 afr[4][2], bfr[3][2];

  const int NT = K >> 6;                         // K-tiles (NT >= 2)

#define ST_A(nb, h, kt)                                                        \
  do {                                                                         \
    GLOAD_LDS16(gA + (size_t)((h) * 128) * lda + ((kt) << 6),                  \
                &As[nb][(h) * 128 + (wave << 3)][0]);                          \
    GLOAD_LDS16(gA + (size_t)((h) * 128 + 64) * lda + ((kt) << 6),             \
                &As[nb][(h) * 128 + 64 + (wave << 3)][0]);                     \
  } while (0)
#define ST_B1(nb, c, kt)                                                       \
  do {                                                                         \
    GLOAD_LDS16(gB + (size_t)((c) * 64) * ldb + ((kt) << 6),                   \
                &Bs[nb][(c) * 64 + (wave << 3)][0]);                           \
  } while (0)

  // A frags i0..3 from rows base_row + i*16 + mrow of As[bf]
#define LDA4(bf, base_row)                                                     \
  do {                                                                         \
    _Pragma("unroll") for (int i_ = 0; i_ < 4; i_++)                           \
      _Pragma("unroll") for (int kk_ = 0; kk_ < 2; kk_++)                      \
        afr[i_][kk_] = *(const short8*)&As[bf][(base_row) + (i_ << 4) + mrow]  \
                            [(((kk_ << 2) | quad) ^ sw) << 3];                 \
  } while (0)
  // B frag j from rows j*64 + wc*16 + mrow of Bs[bf]
#define LDB1(bf, j)                                                            \
  do {                                                                         \
    _Pragma("unroll") for (int kk_ = 0; kk_ < 2; kk_++)                        \
      bfr[j][kk_] = *(const short8*)&Bs[bf][(j) * 64 + (wc << 4) + mrow]       \
          [(((kk_ << 2) | quad) ^ sw) << 3];                                   \
  } while (0)
  // one sub-block: 4 i x 1 j x 2 kk = 8 MFMA (afr holds the i-set for ilo)
#define MMQ8(ilo, j)                                                           \
  do {                                                                         \
    __builtin_amdgcn_s_setprio(1);                                             \
    _Pragma("unroll") for (int kk_ = 0; kk_ < 2; kk_++)                        \
      _Pragma("unroll") for (int i_ = 0; i_ < 4; i_++)                         \
        acc[(ilo) + i_][j] = __builtin_amdgcn_mfma_f32_16x16x32_bf16(          \
            afr[i_][kk_], bfr[j][kk_], acc[(ilo) + i_][j], 0, 0, 0);           \
    __builtin_amdgcn_s_setprio(0);                                             \
  } while (0)

  // prologue: stage tile 0 in FIFO order g1..g7
  ST_A(0, 0, 0); ST_B1(0, 0, 0); ST_B1(0, 1, 0); ST_B1(0, 2, 0); ST_A(0, 1, 0);
  WAITV(3);                                    // g1..g4 resident for P1
  BAR;

  for (int kt = 0; kt < NT - 1; kt++) {
    const int bf = kt & 1, nb = bf ^ 1;
    // ---- P1: reads g1..g4(kt); issues g1..g3(kt+1) ----
    LDA4(bf, (wr << 6));                       // A-h0 rows
    LDB1(bf, 0);                               // B-c0
    LDB1(bf, 1);                               // B-c1
    ST_A(nb, 0, kt + 1);                       // g1',g2'
    ST_B1(nb, 0, kt + 1);                      // g3'
    WAITV(3);                                  // kt g5..g7 resident (P2 reads)
    BAR;
    MMQ8(0, 0);
    MMQ8(0, 1);
    // ---- P2: reads g5..g7(kt); issues g4,g5(kt+1) ----
    LDB1(bf, 2);                               // B-c2
    ST_B1(nb, 1, kt + 1);                      // g4'
    ST_B1(nb, 2, kt + 1);                      // g5'
    BAR;                                       // no wait: P3 reads nothing
    MMQ8(0, 2);
    LDA4(bf, 128 + (wr << 6));                 // A-h1 (g6,g7 resident via P1 wait)
    MMQ8(4, 0);
    // ---- P3: register-only; issues g6,g7(kt+1) ----
    ST_A(nb, 1, kt + 1);                       // g6',g7'
    WAITV(3);                                  // kt+1 g1..g4 resident (next P1)
    BAR;
    MMQ8(4, 1);
    MMQ8(4, 2);
  }
  {                                            // last tile, no staging
    const int bf = (NT - 1) & 1;
    LDA4(bf, (wr << 6));
    LDB1(bf, 0);
    LDB1(bf, 1);
    WAITV(0);                                  // g5..g7 resident
    BAR;
    MMQ8(0, 0);
    MMQ8(0, 1);
    LDB1(bf, 2);
    BAR;
    MMQ8(0, 2);
    LDA4(bf, 128 + (wr << 6));
    MMQ8(4, 0);
    BAR;
    MMQ8(4, 1);
    MMQ8(4, 2);
  }

  // epilogue with fused RoPE.  C/D layout: col = lane&15, row = quad*4 + reg.
  // Pair (even,odd) channels = lanes (mrow, mrow^1): partner via shfl_xor(.,1).
  // Predicates wave-uniform (64-aligned boundaries) -> no divergence.
#pragma unroll
  for (int i = 0; i < 8; i++) {
    int row0 = m0 + ((i >= 4) ? 128 : 0) + (wr << 6) + ((i & 3) << 4) + (quad << 2);
#pragma unroll
    for (int j = 0; j < 3; j++) {
      int col = n0 + j * 64 + (wc << 4) + mrow;
      if (col < 4096) {                        // Q or K: apply RoPE
        const float scale = (col < 2048) ? 0.12751743f : 1.0f;  // log2e/sqrt(128) on Q
        const int p = (col & 127) >> 1;        // rotary pair index within head
#pragma unroll
        for (int r = 0; r < 4; r++) {
          int s = row0 + r;
          float c  = cs[(s << 6) | p];
          float si = sn[(s << 6) | p];
          float v  = acc[i][j][r];
          float pv = __shfl_xor(v, 1);         // partner channel (same row)
          float out = (col & 1) ? (pv * si + v * c)   // odd:  e*sin + o*cos
                                : (v * c - pv * si);  // even: e*cos - o*sin
          C[(size_t)s * ldc + col] = f2bf(out * scale);
        }
      } else {                                 // V: passthrough
#pragma unroll
        for (int r = 0; r < 4; r++)
          C[(size_t)(row0 + r) * ldc + col] = f2bf(acc[i][j][r]);
      }
    }
  }
#undef ST_A
#undef ST_B1
#undef LDA4
#undef LDB1
#undef MMQ8
}

// ---------------------------------------------------------------------------
// Output projection: out[m][n] = sum_k AT[m][k]*WOb[n][k], fp32 out direct.
// 128x128 tile, 256 blocks (full fill), 2 blocks/CU, 2-phase counted vmcnt.
// (Exact R5 form — measured best.)
// ---------------------------------------------------------------------------
__global__ __launch_bounds__(256, 2) void gemm_out(
    const u16* __restrict__ A, const u16* __restrict__ B,
    float* __restrict__ C) {
  // bijective XCD swizzle over 256 blocks
  const int wg = ((int)blockIdx.x & 7) * 32 + ((int)blockIdx.x >> 3);
  const int m0 = (wg >> 4) << 7;
  const int n0 = (wg & 15) << 7;

  __shared__ __align__(16) u16 As[2][128][64];
  __shared__ __align__(16) u16 Bs[2][128][64];

  const int t = threadIdx.x;
  const int lane = t & 63;
  const int wave = t >> 6;           // 0..3
  const int wr = wave >> 1;          // 0..1
  const int wc = wave & 1;           // 0..1
  const int quad = lane >> 4;
  const int mrow = lane & 15;
  const int sw = mrow & 7;

  const int srow = lane >> 3;                    // 0..7
  const int gso  = ((lane & 7) ^ srow) << 3;     // pre-swizzled col seg

  const u16* gA = A + (size_t)(m0 + (wave << 3) + srow) * 2048 + gso;
  const u16* gB = B + (size_t)(n0 + (wave << 3) + srow) * 2048 + gso;

  floatx4 acc[4][4] = {};
  short8 afr[4][2], bfr[4][2];

  const int NT = 32;                             // 2048/64

#define OST_A(nb, p, kt)                                                       \
  GLOAD_LDS16(gA + (size_t)((p) * 32) * 2048 + ((kt) << 6),                    \
              &As[nb][(p) * 32 + (wave << 3)][0])
#define OST_B(nb, p, kt)                                                       \
  GLOAD_LDS16(gB + (size_t)((p) * 32) * 2048 + ((kt) << 6),                    \
              &Bs[nb][(p) * 32 + (wave << 3)][0])

#define OLDA(bf)                                                               \
  do {                                                                         \
    _Pragma("unroll") for (int i_ = 0; i_ < 4; i_++)                           \
      _Pragma("unroll") for (int kk_ = 0; kk_ < 2; kk_++)                      \
        afr[i_][kk_] = *(const short8*)&As[bf][(wr << 6) + (i_ << 4) + mrow]   \
                            [(((kk_ << 2) | quad) ^ sw) << 3];                 \
  } while (0)
#define OLDB2(bf, jlo)                                                         \
  do {                                                                         \
    _Pragma("unroll") for (int j_ = 0; j_ < 2; j_++)                           \
      _Pragma("unroll") for (int kk_ = 0; kk_ < 2; kk_++)                      \
        bfr[(jlo) + j_][kk_] =                                                 \
            *(const short8*)&Bs[bf][(wc << 6) + (((jlo) + j_) << 4) + mrow]    \
                [(((kk_ << 2) | quad) ^ sw) << 3];                             \
  } while (0)
#define OMM16(jlo)                                                             \
  do {                                                                         \
    __builtin_amdgcn_s_setprio(1);                                             \
    _Pragma("unroll") for (int kk_ = 0; kk_ < 2; kk_++)                        \
      _Pragma("unroll") for (int i_ = 0; i_ < 4; i_++)                         \
        _Pragma("unroll") for (int j_ = 0; j_ < 2; j_++)                       \
          acc[i_][(jlo) + j_] = __builtin_amdgcn_mfma_f32_16x16x32_bf16(       \
              afr[i_][kk_], bfr[(jlo) + j_][kk_], acc[i_][(jlo) + j_], 0, 0, 0);\
    __builtin_amdgcn_s_setprio(0);                                             \
  } while (0)

  // prologue: FIFO g1..g8 = A0,A1,A2,A3,B0,B2,B1,B3
  OST_A(0, 0, 0); OST_A(0, 1, 0); OST_A(0, 2, 0); OST_A(0, 3, 0);
  OST_B(0, 0, 0); OST_B(0, 2, 0); OST_B(0, 1, 0); OST_B(0, 3, 0);
  WAITV(2);                                    // g1..g6 resident for P1
  BAR;

  for (int kt = 0; kt < NT - 1; kt++) {
    const int bf = kt & 1, nb = bf ^ 1;
    // ---- P1 ----
    OLDA(bf);
    OLDB2(bf, 0);
    OST_A(nb, 0, kt + 1); OST_A(nb, 1, kt + 1);
    OST_A(nb, 2, kt + 1); OST_A(nb, 3, kt + 1);
    OST_B(nb, 0, kt + 1); OST_B(nb, 2, kt + 1);
    WAITV(6);                                  // g7,g8(kt) resident
    BAR;
    OMM16(0);
    // ---- P2 ----
    OLDB2(bf, 2);
    OST_B(nb, 1, kt + 1); OST_B(nb, 3, kt + 1);
    WAITV(2);                                  // g1'..g6' resident (next P1)
    BAR;
    OMM16(2);
  }
  {                                            // last tile, no staging
    const int bf = (NT - 1) & 1;
    OLDA(bf);
    OLDB2(bf, 0);
    WAITV(0);                                  // g7,g8 resident
    BAR;
    OMM16(0);
    OLDB2(bf, 2);
    OMM16(2);
  }

  // epilogue: fp32 direct. C/D layout: col = lane&15, row = quad*4 + reg
#pragma unroll
  for (int i = 0; i < 4; i++) {
    int row0 = m0 + (wr << 6) + (i << 4) + (quad << 2);
#pragma unroll
    for (int j = 0; j < 4; j++) {
      int col = n0 + (wc << 6) + (j << 4) + mrow;
#pragma unroll
      for (int r = 0; r < 4; r++)
        C[(size_t)(row0 + r) * 2048 + col] = acc[i][j][r];
    }
  }
#undef OST_A
#undef OST_B
#undef OLDA
#undef OLDB2
#undef OMM16
}

// ---------------------------------------------------------------------------
// Transpose V (cols 4096..6143 of QKV, ld 6144) -> VT[d][s] (ld 2048).
// R11: rope removed from this kernel (fused into gemm256's epilogue) —
// back to the plain 1024-block transpose.
// ---------------------------------------------------------------------------
__global__ __launch_bounds__(256) void transpose_v(const u16* __restrict__ src,
                                                   u16* __restrict__ dst) {
  __shared__ u16 tile[64][68];
  const int d0 = blockIdx.x << 6;
  const int s0 = blockIdx.y << 6;
  const int tx = (threadIdx.x & 15) << 2;
  const int ty = threadIdx.x >> 4;
#pragma unroll
  for (int rr = 0; rr < 64; rr += 16) {
    ushortx4 v = *(const ushortx4*)(src + (size_t)(s0 + ty + rr) * 6144 + d0 + tx);
    *(ushortx4*)&tile[ty + rr][tx] = v;
  }
  __syncthreads();
#pragma unroll
  for (int rr = 0; rr < 64; rr += 16) {
    int r = ty + rr;
    ushortx4 o;
    o.x = tile[tx + 0][r]; o.y = tile[tx + 1][r];
    o.z = tile[tx + 2][r]; o.w = tile[tx + 3][r];
    *(ushortx4*)(dst + (size_t)(d0 + r) * 2048 + s0 + tx) = o;
  }
}

// ---------------------------------------------------------------------------
// Flash attention v6 (unchanged; best-measured config).  512 blocks,
// 2 blocks/CU; complementary-pair block mapping; K(t+1) staged at B3 under
// PV, V(t+1) at B1 under QK^T, counted vmcnt(8).
// ---------------------------------------------------------------------------
__global__ __launch_bounds__(256, 2) void flash_attn(
    const u16* __restrict__ QKVp, const u16* __restrict__ VTp,
    u16* __restrict__ ATp) {
  const int bid  = (int)blockIdx.x;
  const int g    = (bid & 255) >> 4;            // 0..15
  const int h    = bid & 15;
  const int qsub = (bid >> 8) ? g : 31 - g;     // complementary pairing
  const int q0 = qsub << 6;
  const int ktmax = qsub >> 1;

  __shared__ __align__(16) u16 Ks[128][128];    // K tile [s][d]   (32 KB)
  __shared__ __align__(16) u16 Vs[128][128];    // VT tile [d][s]  (32 KB)
  __shared__ __align__(16) u16 Ps[64][128];     // P tile  [q][s]  (16 KB)

  const int t = threadIdx.x;
  const int lane = t & 63;
  const int wave = t >> 6;
  const int quad = lane >> 4;
  const int mrow = lane & 15;
  const int sw   = mrow & 7;
  const int wmS = (wave & 1) << 5;
  const int wnS = (wave >> 1) << 6;
  const int wmV = (wave >> 1) << 6;
  const int wnP = (wave & 1) << 5;

  const int r4  = lane >> 4;
  const int seg = lane & 15;
  const int c0 = ((seg ^ r4) << 3);
  const int c4 = ((seg ^ (r4 + 4)) << 3);

  const u16* qbase = QKVp + (size_t)q0 * 6144 + (h << 7);
  const u16* kbase = QKVp + 2048 + (h << 7);
  const u16* vbase = VTp + (size_t)(h << 7) * 2048;

#define STAGE_K(kt)                                                            \
  do {                                                                         \
    int rr0_ = wave << 5;                                                      \
    _Pragma("unroll") for (int ii_ = 0; ii_ < 8; ii_++) {                      \
      int rr_ = rr0_ + (ii_ << 2);                                             \
      GLOAD_LDS16(kbase + (size_t)(((kt) << 7) + rr_ + r4) * 6144 +            \
                      ((ii_ & 1) ? c4 : c0),                                   \
                  &Ks[rr_][0]);                                                \
    }                                                                          \
  } while (0)
#define STAGE_V(kt)                                                            \
  do {                                                                         \
    int rr0_ = wave << 5;                                                      \
    _Pragma("unroll") for (int ii_ = 0; ii_ < 8; ii_++) {                      \
      int rr_ = rr0_ + (ii_ << 2);                                             \
      GLOAD_LDS16(vbase + (size_t)(rr_ + r4) * 2048 + ((kt) << 7) +            \
                      ((ii_ & 1) ? c4 : c0),                                   \
                  &Vs[rr_][0]);                                                \
    }                                                                          \
  } while (0)

  short8 aq[2][4];
#pragma unroll
  for (int i = 0; i < 2; i++)
#pragma unroll
    for (int kk = 0; kk < 4; kk++)
      aq[i][kk] = *(const short8*)(qbase + (size_t)(wmS + (i << 4) + mrow) * 6144 +
                                   (kk << 5) + (quad << 3));

  const short8 ones = {0x3F80, 0x3F80, 0x3F80, 0x3F80,
                       0x3F80, 0x3F80, 0x3F80, 0x3F80};   // bf16 1.0 x8

  floatx4 Oa[4][2] = {};                        // O^T tile (d x q)
  floatx4 Oa1[2] = {};                          // row-sums l

  const float C2 = 23.083120654223414f;         // 16*log2(e)

  STAGE_K(0);
  STAGE_V(0);
  WAITV(8);                                     // K(0) resident (this wave)
  BAR;                                          // K(0) resident (all waves)

  for (int kt = 0; kt <= ktmax; kt++) {
    // ---- S-phase: S' = Q'.K^T (V(kt) gloads still in flight) ----
    floatx4 sa[2][4] = {};
#pragma unroll
    for (int kk = 0; kk < 4; kk++) {
      short8 bk[4];
#pragma unroll
      for (int j = 0; j < 4; j++)
        bk[j] = *(const short8*)&Ks[wnS + (j << 4) + mrow][(((kk << 2) | quad) ^ sw) << 3];
      __builtin_amdgcn_s_setprio(1);
#pragma unroll
      for (int i = 0; i < 2; i++)
#pragma unroll
        for (int j = 0; j < 4; j++)
          sa[i][j] = __builtin_amdgcn_mfma_f32_16x16x32_bf16(aq[i][kk], bk[j], sa[i][j], 0, 0, 0);
      __builtin_amdgcn_s_setprio(0);
    }
    if (kt == ktmax) {                          // causal mask on diagonal tile
#pragma unroll
      for (int i = 0; i < 2; i++)
#pragma unroll
        for (int j = 0; j < 4; j++)
#pragma unroll
          for (int r = 0; r < 4; r++) {
            int ql = q0 + wmS + (i << 4) + (quad << 2) + r;
            int sl = (kt << 7) + wnS + (j << 4) + mrow;
            if (sl > ql) sa[i][j][r] = -1e30f;  // exp2 -> exact 0
          }
    }
#pragma unroll
    for (int i = 0; i < 2; i++)
#pragma unroll
      for (int j = 0; j < 4; j++)
#pragma unroll
        for (int r = 0; r < 4; r++) {
          int row = wmS + (i << 4) + (quad << 2) + r;
          int col = wnS + (j << 4) + mrow;
          Ps[row][((((col >> 3) ^ (row & 7)) << 3) | (col & 7))] =
              f2bf(EXP2F(sa[i][j][r] - C2));
        }
    WAITV(0);                                   // V(kt) resident (this wave)
    WAITL;                                      // Ps write + Ks reads retired
    BAR;  // B3: Ps visible, Vs resident, all waves' Ks reads done

    if (kt < ktmax) STAGE_K(kt + 1);            // lands under PV's MFMAs

    // ---- PV: O^T[d][q] += VT.P^T ; l[q] += ones.P^T ----
#pragma unroll
    for (int kk = 0; kk < 4; kk++) {
      short8 av[4], bp[2];
#pragma unroll
      for (int i = 0; i < 4; i++)
        av[i] = *(const short8*)&Vs[wmV + (i << 4) + mrow][(((kk << 2) | quad) ^ sw) << 3];
#pragma unroll
      for (int j = 0; j < 2; j++)
        bp[j] = *(const short8*)&Ps[wnP + (j << 4) + mrow][(((kk << 2) | quad) ^ sw) << 3];
      __builtin_amdgcn_s_setprio(1);
#pragma unroll
      for (int i = 0; i < 4; i++)
#pragma unroll
        for (int j = 0; j < 2; j++)
          Oa[i][j] = __builtin_amdgcn_mfma_f32_16x16x32_bf16(av[i], bp[j], Oa[i][j], 0, 0, 0);
#pragma unroll
      for (int j = 0; j < 2; j++)
        Oa1[j] = __builtin_amdgcn_mfma_f32_16x16x32_bf16(ones, bp[j], Oa1[j], 0, 0, 0);
      __builtin_amdgcn_s_setprio(0);
    }
    WAITL;                                      // Vs/Ps reads retired
    BAR;  // B1: all waves done reading Vs/Ps

    if (kt < ktmax) STAGE_V(kt + 1);            // lands under next QK^T
    WAITV(8);                                   // K(kt+1) resident (this wave)
    BAR;  // B2: K(kt+1) resident (all waves)
  }
#undef STAGE_K
#undef STAGE_V

  // epilogue: AT[(h*128+d)][q0+q] = O/l, bf16
  float linv[2];
#pragma unroll
  for (int j = 0; j < 2; j++) linv[j] = 1.f / Oa1[j][0];
#pragma unroll
  for (int i = 0; i < 4; i++) {
    int drow = (h << 7) + wmV + (i << 4) + (quad << 2);
#pragma unroll
    for (int j = 0; j < 2; j++) {
      int col = q0 + wnP + (j << 4) + mrow;
#pragma unroll
      for (int r = 0; r < 4; r++)
        ATp[(size_t)(drow + r) * 2048 + col] = f2bf(Oa[i][j][r] * linv[j]);
    }
  }
}

// ---------------------------------------------------------------------------
// Orchestration:
//   QKV = BT256x192(x, [wq;wk;wv]) with RoPE fused in the epilogue;
//   VT  = transpose(V);
//   AT  = flash_attn (512 blocks, complementary-pair balanced);
//   out = gemm_out(AT, wo)  [128^2 tiles, 256 blocks, fp32 direct].
// ---------------------------------------------------------------------------
extern "C" void kernel_launch(void* const* d_in, const int* in_sizes, int n_in,
                              void* d_out, int out_size, void* d_ws, size_t ws_size,
                              hipStream_t stream) {
  const float* x  = (const float*)d_in[0];
  const float* fc = (const float*)d_in[1];
  const float* fs = (const float*)d_in[2];
  const float* wq = (const float*)d_in[4];
  const float* wk = (const float*)d_in[5];
  const float* wv = (const float*)d_in[6];
  const float* wo = (const float*)d_in[7];
  float* out = (float*)d_out;

  char* ws = (char*)d_ws;
  const size_t MB = 1024 * 1024;
  u16*   XB   = (u16*)(ws + 0 * MB);
  u16*   WQKV = (u16*)(ws + 8 * MB);     // [wq;wk;wv] 6144x2048
  u16*   WOb  = (u16*)(ws + 32 * MB);
  u16*   QKV  = (u16*)(ws + 40 * MB);    // [s][6144]
  u16*   VT   = (u16*)(ws + 64 * MB);    // [d][s]
  u16*   AT   = (u16*)(ws + 72 * MB);    // [(h*128+d)][q]

  dim3 blk(256);
  cvt_all<<<dim3(4096, 5), blk, 0, stream>>>(
      (const floatx4*)x, (const floatx4*)wq, (const floatx4*)wk,
      (const floatx4*)wv, (const floatx4*)wo,
      (ushortx4*)XB, (ushortx4*)WQKV, (ushortx4*)WOb);

  // fused QKV projection + RoPE: M=2048, N=6144, K=2048 — 256x192 tiles,
  // 8 x 32 = 256 blocks (exactly 1/CU), 512 threads.
  gemm256_bt<<<dim3(256), dim3(512), 0, stream>>>(XB, WQKV, QKV,
                                                  6144, 2048, 2048, 2048, 6144,
                                                  fc, fs);

  transpose_v<<<dim3(32, 32), blk, 0, stream>>>(QKV + 4096, VT);

  flash_attn<<<dim3(512), blk, 0, stream>>>(QKV, VT, AT);

  // final projection: out[r][j] = sum_q AT[r][q] * wo[j][q], fp32 direct
  gemm_out<<<dim3(256), blk, 0, stream>>>(AT, WOb, out);
}